// Round 12
// baseline (125.371 us; speedup 1.0000x reference)
//
#include <hip/hip_runtime.h>
#include <hip/hip_bf16.h>
#include <math.h>

// CrossGeometricStructureEmbedding, round 19.
// R16/R17/R18 post-mortem: three nulls (occupancy up, traffic halved - both
// counter-verified) => kernel is bound by the barrier-lockstep phase
// structure, not by LDS or occupancy. The E-LDS round trip exists only to
// SHARE sincos across waves; regenerating E in-registers in the A-frag
// layout costs 112 trans/pt-type/wave (4x duplication at 64-col waves) =
// ~5.5us trans-pipe/CU - comparable to the LDS pipe it replaces - and
// deletes ALL phase barriers, fills, double-buffers, and E ds_reads. After
// one anchor barrier, waves free-run; gen(ks+1) overlaps mfma(ks).
// Mechanics: lane needs A-row (l&31)+32hh -> x = __shfl(xd, l5+32hh);
// afr = fill_chunk's exact math at ch=2ks+half (factor fb(half)*10^(-ks/4),
// within-chunk 10^(-j/32); aug = ks==6 && half==1 -> [x,x2,x3,x4,1,0,0,0]).
// Tiling: 64 cols x 64 anchors/wave, 2 pts in flight (pg=wave>>2), 4 pts/
// wave; bw[2][7]+acc[2] under the R13-PROVEN (512,4) spill-free envelope;
// dm in regs; out direct. Prep rewritten: 1 wave/row, lane-parallel terms
// (d_i = exp2f per lane), shfl_xor butterfly reduce, coalesced loads.
// Predict: conflicts 3.67M -> ~0 (signature), WRITE_SIZE 4096 (spill gate,
// read first; fallback R16), kernel ~12-16us, bench ~80-88, VALUBusy top
// pipe, absmax 0.015625. If ~95+: trans-rate wrong -> cols 64->128 next.

typedef __attribute__((ext_vector_type(8))) short short8;
typedef __attribute__((ext_vector_type(16))) float f32x16;
typedef __attribute__((ext_vector_type(4))) unsigned int uint4v;
typedef __attribute__((ext_vector_type(4))) float float4v;
typedef __attribute__((ext_vector_type(4))) unsigned short ushort4v;

#define HH 256
#define KK 112
#define NPTS 4096

__device__ __forceinline__ unsigned short f2bf(float f) {
    union { float f; unsigned int u; } v; v.f = f;
    unsigned int r = v.u + 0x7fffu + ((v.u >> 16) & 1u);  // RNE
    return (unsigned short)(r >> 16);
}

__device__ __forceinline__ unsigned int pack_sc(float s, float c) {
    union { __hip_bfloat162 h; unsigned int u; } v;
    v.h = __float22bfloat162_rn(make_float2(s, c));  // low = even elem, high = odd
    return v.u;
}

// Build trimmed+augmented W: wbf[(t*256+o)*112 + e]
//   e in [0,104): W[o][e] bf16 (pairs 0..51)
//   e=104..108: u1,u2,u3,u4,v; [109,112): 0   (R13-verified fold, cutoff 52)
// One wave per row: lanes hold terms i=52+lane (+116+lane for lane<12),
// butterfly-reduced; lanes 0..25 do the coalesced trim copy.
__global__ __launch_bounds__(64)
void prep_w_kernel(const float* __restrict__ Wa, const float* __restrict__ Wd,
                   unsigned short* __restrict__ wbf) {
    const int row = blockIdx.x;            // 0..511 = t*256 + o
    const int t = row >> 8, o = row & 255;
    const int lane = threadIdx.x;
    const float* W = (t == 0 ? Wd : Wa) + o * HH;
    unsigned short* dst = wbf + row * KK;

    if (lane < 26) {  // 104 elems as float4
        const float4v w4 = ((const float4v*)W)[lane];
        ushort4v s4;
        #pragma unroll
        for (int j = 0; j < 4; ++j) s4[j] = f2bf(w4[j]);
        ((ushort4v*)dst)[lane] = s4;
    }

    float u1, u2, u3, u4, v;
    {
        const int i = 52 + lane;  // 52..115
        const float d = exp2f(-(float)i * 0.10381025296523008f);  // 10^(-i/32)
        const float d2 = d * d;
        const float ws = W[2 * i], wc = W[2 * i + 1];
        u1 = d * ws;
        u3 = -(d * d2) * (1.0f / 6.0f) * ws;
        u2 = -0.5f * d2 * wc;
        u4 = (d2 * d2) * (1.0f / 24.0f) * wc;
        v  = wc;
    }
    if (lane < 12) {
        const int i = 116 + lane;  // 116..127
        const float d = exp2f(-(float)i * 0.10381025296523008f);
        const float d2 = d * d;
        const float ws = W[2 * i], wc = W[2 * i + 1];
        u1 += d * ws;
        u3 += -(d * d2) * (1.0f / 6.0f) * ws;
        u2 += -0.5f * d2 * wc;
        u4 += (d2 * d2) * (1.0f / 24.0f) * wc;
        v  += wc;
    }
    #pragma unroll
    for (int off = 32; off; off >>= 1) {
        u1 += __shfl_xor(u1, off);
        u2 += __shfl_xor(u2, off);
        u3 += __shfl_xor(u3, off);
        u4 += __shfl_xor(u4, off);
        v  += __shfl_xor(v, off);
    }
    if (lane == 0) {
        dst[104] = f2bf(u1);
        dst[105] = f2bf(u2);
        dst[106] = f2bf(u3);
        dst[107] = f2bf(u4);
        dst[108] = f2bf(v);
        dst[109] = 0; dst[110] = 0; dst[111] = 0;
    }
}

__global__ __launch_bounds__(512, 4)
void cgse_main(const float* __restrict__ points,
               const float* __restrict__ anchors,
               const unsigned short* __restrict__ wbf,
               const float* __restrict__ ba,
               const float* __restrict__ bd,
               float* __restrict__ out) {
    __shared__ float anch[192];

    const int tid = threadIdx.x;
    const int wave = tid >> 6, lane = tid & 63;
    const int l5 = lane & 31, half = lane >> 5;
    const int pg = wave >> 2;   // point parity: waves 0-3 -> pt 2pl, 4-7 -> 2pl+1
    const int w4 = wave & 3;    // wave's 64-col strip
    const int base = blockIdx.x * 8;

    if (tid < 192) anch[tid] = anchors[tid];
    __syncthreads();  // the ONLY barrier

    float bias[2];
    #pragma unroll
    for (int ntp = 0; ntp < 2; ++ntp) {
        const int c = w4 * 64 + ntp * 32 + l5;
        bias[ntp] = ba[c] + bd[c];
    }

    // (1/2pi) * 10^(-half/8): A-elem e=16ks+8half+j -> pair p=8ks+4half+(j>>1)
    const float fb = half ? 0.11936620731892151f : 0.15915494309189535f;
    // 10^(-ks/4), folds to immediates in the unrolled ks loop
    const float KS[7] = {1.0f, 0.5623413251903491f, 0.31622776601683794f,
                         0.17782794100389228f, 0.1f, 0.05623413251903491f,
                         0.031622776601683794f};

    // ---- W strips for the wave's 2 col-tiles: 2 x 7 x short8 = 56 VGPRs
    short8 bw[2][7];
    auto loadW = [&](int t) {
        #pragma unroll
        for (int ntp = 0; ntp < 2; ++ntp) {
            const unsigned short* wr =
                wbf + (t * HH + w4 * 64 + ntp * 32 + l5) * KK + half * 8;
            #pragma unroll
            for (int ks = 0; ks < 7; ++ks)
                bw[ntp][ks] = *(const short8*)(wr + ks * 16);
        }
    };

    // geometry for point pn, lane = anchor k (R8-verified math)
    auto geom = [&](int pn, float& xd, float& xa) {
        const int k2 = (lane + 1) & 63;
        const float px = points[pn * 3 + 0], py = points[pn * 3 + 1], pz = points[pn * 3 + 2];
        const float r1x = px - anch[lane * 3 + 0];
        const float r1y = py - anch[lane * 3 + 1];
        const float r1z = pz - anch[lane * 3 + 2];
        const float r2x = px - anch[k2 * 3 + 0];
        const float r2y = py - anch[k2 * 3 + 1];
        const float r2z = pz - anch[k2 * 3 + 2];
        xd = sqrtf(r1x * r1x + r1y * r1y + r1z * r1z) * 5.0f;  // /SIGMA_D
        const float cx = r1y * r2z - r1z * r2y;
        const float cy = r1z * r2x - r1x * r2z;
        const float cz = r1x * r2y - r1y * r2x;
        const float sv = sqrtf(cx * cx + cy * cy + cz * cz);
        const float cv = r1x * r2x + r1y * r2y + r1z * r2z;
        xa = atan2f(sv, cv) * 3.8197186342054885f;  // *180/(15*pi)
    };

    // A-frag gen in-lane: elems e=16ks+8half+(0..7) of E-row (l&31)+32hh.
    // Same math as the verified fill_chunk at chunk ch = 2ks+half.
    auto genA = [&](float tb, float xr, int ks) -> short8 {
        uint4v w;
        if (half && ks == 6) {  // elems 104..111: [x,x^2,x^3,x^4,1,0,0,0]
            const float x2 = xr * xr;
            w[0] = pack_sc(xr, x2);
            w[1] = pack_sc(x2 * xr, x2 * x2);
            w[2] = pack_sc(1.0f, 0.0f);
            w[3] = 0u;
        } else {
            const float t0 = tb * KS[ks];
            const float t[4] = {t0, t0 * 0.9305720409297085f,
                                t0 * 0.8659643233600653f, t0 * 0.8058421877614819f};
            #pragma unroll
            for (int j = 0; j < 4; ++j)
                w[j] = pack_sc(__builtin_amdgcn_sinf(t[j]), __builtin_amdgcn_cosf(t[j]));
        }
        return *(short8*)&w;
    };

    // max over one anchor-half: 16 acc regs -> scalar (max3-shaped tree)
    auto htree = [&](const f32x16& a) -> float {
        const float v0 = fmaxf(fmaxf(a[0], a[1]), a[2]);
        const float v1 = fmaxf(fmaxf(a[3], a[4]), a[5]);
        const float v2 = fmaxf(fmaxf(a[6], a[7]), a[8]);
        const float v3 = fmaxf(fmaxf(a[9], a[10]), a[11]);
        const float v4 = fmaxf(fmaxf(a[12], a[13]), a[14]);
        const float w0 = fmaxf(fmaxf(v0, v1), v2);
        const float w1 = fmaxf(fmaxf(v3, v4), a[15]);
        return fmaxf(w0, w1);
    };

    // full 64-anchor x 64-col max for one point-type; x = per-lane(=anchor) idx
    auto ptmax = [&](float x, float m[2]) {
        #pragma unroll
        for (int hh = 0; hh < 2; ++hh) {
            const float xv = __shfl(x, l5 + 32 * hh);  // this lane's A-row value
            const float tb = xv * fb;
            f32x16 acc0, acc1;
            #pragma unroll
            for (int r = 0; r < 16; ++r) { acc0[r] = 0.f; acc1[r] = 0.f; }
            #pragma unroll
            for (int ks = 0; ks < 7; ++ks) {
                const short8 afr = genA(tb, xv, ks);
                __builtin_amdgcn_s_setprio(1);
                acc0 = __builtin_amdgcn_mfma_f32_32x32x16_bf16(afr, bw[0][ks], acc0, 0, 0, 0);
                acc1 = __builtin_amdgcn_mfma_f32_32x32x16_bf16(afr, bw[1][ks], acc1, 0, 0, 0);
                __builtin_amdgcn_s_setprio(0);
            }
            const float h0 = htree(acc0), h1 = htree(acc1);
            if (hh == 0) { m[0] = h0; m[1] = h1; }
            else { m[0] = fmaxf(m[0], h0); m[1] = fmaxf(m[1], h1); }
        }
        m[0] = fmaxf(m[0], __shfl_down(m[0], 32));
        m[1] = fmaxf(m[1], __shfl_down(m[1], 32));
    };

    float dm[4][2];  // d-pass maxes, statically indexed

    loadW(0);
    #pragma unroll
    for (int pl = 0; pl < 4; ++pl) {
        float xd, xa;
        geom(base + 2 * pl + pg, xd, xa);
        float m[2];
        ptmax(xd, m);
        dm[pl][0] = m[0]; dm[pl][1] = m[1];  // valid on lanes 0..31
    }

    loadW(1);
    #pragma unroll
    for (int pl = 0; pl < 4; ++pl) {
        const int pn = base + 2 * pl + pg;
        float xd, xa;
        geom(pn, xd, xa);  // recompute (cheaper than 8 live regs)
        float m[2];
        ptmax(xa, m);
        if (lane < 32) {
            out[pn * HH + w4 * 64 + l5]      = m[0] + dm[pl][0] + bias[0];
            out[pn * HH + w4 * 64 + 32 + l5] = m[1] + dm[pl][1] + bias[1];
        }
    }
}

extern "C" void kernel_launch(void* const* d_in, const int* in_sizes, int n_in,
                              void* d_out, int out_size, void* d_ws, size_t ws_size,
                              hipStream_t stream) {
    const float* points  = (const float*)d_in[0];
    const float* anchors = (const float*)d_in[1];
    // d_in[2] = cor_score: unused by the reference
    const float* Wa = (const float*)d_in[3];
    const float* ba = (const float*)d_in[4];
    const float* Wd = (const float*)d_in[5];
    const float* bd = (const float*)d_in[6];

    unsigned short* wbf = (unsigned short*)d_ws;  // 112 KB: trimmed+aug Wd|Wa bf16

    hipLaunchKernelGGL(prep_w_kernel, dim3(512), dim3(64), 0, stream, Wa, Wd, wbf);
    hipLaunchKernelGGL(cgse_main, dim3(NPTS / 8), dim3(512), 0, stream,
                       points, anchors, wbf, ba, bd, (float*)d_out);
}

// Round 13
// 114.557 us; speedup vs baseline: 1.0944x; 1.0944x over previous
//
#include <hip/hip_runtime.h>
#include <hip/hip_bf16.h>
#include <math.h>

// CrossGeometricStructureEmbedding, round 20.
// R19 post-mortem: the in-register-E concept never ran unspilled - hipcc's
// 2nd launch_bounds arg on 512-thr blocks empirically caps VGPR at
// 2048/(8*arg) (measured: arg2->128, arg4->64, arg6->40 across R10-R19),
// so (512,4) imposed a 64-reg cap on a ~116-reg working set -> 57MB scratch
// (WRITE 61.7MB), 68us. Everything else verified: conflicts -> 0, absmax
// unchanged. R20 = R19 with (512,2): the R10/R11-proven 128-reg config.
// 16 free-running waves/CU (2 blocks, no phase barriers); trans ~6us +
// VALU ~5us + MFMA ~4.3us per CU, overlappable with no lockstep.
// GATES in order: WRITE_SIZE must be 4096KB exactly / FETCH ~1.3MB (no
// scratch); VGPR 110-128; conflicts ~0. Predict kernel ~15-20us, bench
// ~85-92, VALUBusy top pipe ~55-65, absmax 0.015625. If unspilled but
// >25us: trans duplication is the wall -> colwidth 128 next.

typedef __attribute__((ext_vector_type(8))) short short8;
typedef __attribute__((ext_vector_type(16))) float f32x16;
typedef __attribute__((ext_vector_type(4))) unsigned int uint4v;
typedef __attribute__((ext_vector_type(4))) float float4v;
typedef __attribute__((ext_vector_type(4))) unsigned short ushort4v;

#define HH 256
#define KK 112
#define NPTS 4096

__device__ __forceinline__ unsigned short f2bf(float f) {
    union { float f; unsigned int u; } v; v.f = f;
    unsigned int r = v.u + 0x7fffu + ((v.u >> 16) & 1u);  // RNE
    return (unsigned short)(r >> 16);
}

__device__ __forceinline__ unsigned int pack_sc(float s, float c) {
    union { __hip_bfloat162 h; unsigned int u; } v;
    v.h = __float22bfloat162_rn(make_float2(s, c));  // low = even elem, high = odd
    return v.u;
}

// Build trimmed+augmented W: wbf[(t*256+o)*112 + e]
//   e in [0,104): W[o][e] bf16 (pairs 0..51)
//   e=104..108: u1,u2,u3,u4,v; [109,112): 0   (R13-verified fold, cutoff 52)
// One wave per row: lanes hold terms i=52+lane (+116+lane for lane<12),
// butterfly-reduced; lanes 0..25 do the coalesced trim copy.
__global__ __launch_bounds__(64)
void prep_w_kernel(const float* __restrict__ Wa, const float* __restrict__ Wd,
                   unsigned short* __restrict__ wbf) {
    const int row = blockIdx.x;            // 0..511 = t*256 + o
    const int t = row >> 8, o = row & 255;
    const int lane = threadIdx.x;
    const float* W = (t == 0 ? Wd : Wa) + o * HH;
    unsigned short* dst = wbf + row * KK;

    if (lane < 26) {  // 104 elems as float4
        const float4v w4 = ((const float4v*)W)[lane];
        ushort4v s4;
        #pragma unroll
        for (int j = 0; j < 4; ++j) s4[j] = f2bf(w4[j]);
        ((ushort4v*)dst)[lane] = s4;
    }

    float u1, u2, u3, u4, v;
    {
        const int i = 52 + lane;  // 52..115
        const float d = exp2f(-(float)i * 0.10381025296523008f);  // 10^(-i/32)
        const float d2 = d * d;
        const float ws = W[2 * i], wc = W[2 * i + 1];
        u1 = d * ws;
        u3 = -(d * d2) * (1.0f / 6.0f) * ws;
        u2 = -0.5f * d2 * wc;
        u4 = (d2 * d2) * (1.0f / 24.0f) * wc;
        v  = wc;
    }
    if (lane < 12) {
        const int i = 116 + lane;  // 116..127
        const float d = exp2f(-(float)i * 0.10381025296523008f);
        const float d2 = d * d;
        const float ws = W[2 * i], wc = W[2 * i + 1];
        u1 += d * ws;
        u3 += -(d * d2) * (1.0f / 6.0f) * ws;
        u2 += -0.5f * d2 * wc;
        u4 += (d2 * d2) * (1.0f / 24.0f) * wc;
        v  += wc;
    }
    #pragma unroll
    for (int off = 32; off; off >>= 1) {
        u1 += __shfl_xor(u1, off);
        u2 += __shfl_xor(u2, off);
        u3 += __shfl_xor(u3, off);
        u4 += __shfl_xor(u4, off);
        v  += __shfl_xor(v, off);
    }
    if (lane == 0) {
        dst[104] = f2bf(u1);
        dst[105] = f2bf(u2);
        dst[106] = f2bf(u3);
        dst[107] = f2bf(u4);
        dst[108] = f2bf(v);
        dst[109] = 0; dst[110] = 0; dst[111] = 0;
    }
}

__global__ __launch_bounds__(512, 2)
void cgse_main(const float* __restrict__ points,
               const float* __restrict__ anchors,
               const unsigned short* __restrict__ wbf,
               const float* __restrict__ ba,
               const float* __restrict__ bd,
               float* __restrict__ out) {
    __shared__ float anch[192];

    const int tid = threadIdx.x;
    const int wave = tid >> 6, lane = tid & 63;
    const int l5 = lane & 31, half = lane >> 5;
    const int pg = wave >> 2;   // point parity: waves 0-3 -> pt 2pl, 4-7 -> 2pl+1
    const int w4 = wave & 3;    // wave's 64-col strip
    const int base = blockIdx.x * 8;

    if (tid < 192) anch[tid] = anchors[tid];
    __syncthreads();  // the ONLY barrier

    float bias[2];
    #pragma unroll
    for (int ntp = 0; ntp < 2; ++ntp) {
        const int c = w4 * 64 + ntp * 32 + l5;
        bias[ntp] = ba[c] + bd[c];
    }

    // (1/2pi) * 10^(-half/8): A-elem e=16ks+8half+j -> pair p=8ks+4half+(j>>1)
    const float fb = half ? 0.11936620731892151f : 0.15915494309189535f;
    // 10^(-ks/4), folds to immediates in the unrolled ks loop
    const float KS[7] = {1.0f, 0.5623413251903491f, 0.31622776601683794f,
                         0.17782794100389228f, 0.1f, 0.05623413251903491f,
                         0.031622776601683794f};

    // ---- W strips for the wave's 2 col-tiles: 2 x 7 x short8 = 56 VGPRs
    short8 bw[2][7];
    auto loadW = [&](int t) {
        #pragma unroll
        for (int ntp = 0; ntp < 2; ++ntp) {
            const unsigned short* wr =
                wbf + (t * HH + w4 * 64 + ntp * 32 + l5) * KK + half * 8;
            #pragma unroll
            for (int ks = 0; ks < 7; ++ks)
                bw[ntp][ks] = *(const short8*)(wr + ks * 16);
        }
    };

    // geometry for point pn, lane = anchor k (R8-verified math)
    auto geom = [&](int pn, float& xd, float& xa) {
        const int k2 = (lane + 1) & 63;
        const float px = points[pn * 3 + 0], py = points[pn * 3 + 1], pz = points[pn * 3 + 2];
        const float r1x = px - anch[lane * 3 + 0];
        const float r1y = py - anch[lane * 3 + 1];
        const float r1z = pz - anch[lane * 3 + 2];
        const float r2x = px - anch[k2 * 3 + 0];
        const float r2y = py - anch[k2 * 3 + 1];
        const float r2z = pz - anch[k2 * 3 + 2];
        xd = sqrtf(r1x * r1x + r1y * r1y + r1z * r1z) * 5.0f;  // /SIGMA_D
        const float cx = r1y * r2z - r1z * r2y;
        const float cy = r1z * r2x - r1x * r2z;
        const float cz = r1x * r2y - r1y * r2x;
        const float sv = sqrtf(cx * cx + cy * cy + cz * cz);
        const float cv = r1x * r2x + r1y * r2y + r1z * r2z;
        xa = atan2f(sv, cv) * 3.8197186342054885f;  // *180/(15*pi)
    };

    // A-frag gen in-lane: elems e=16ks+8half+(0..7) of E-row (l&31)+32hh.
    // Same math as the verified fill_chunk at chunk ch = 2ks+half.
    auto genA = [&](float tb, float xr, int ks) -> short8 {
        uint4v w;
        if (half && ks == 6) {  // elems 104..111: [x,x^2,x^3,x^4,1,0,0,0]
            const float x2 = xr * xr;
            w[0] = pack_sc(xr, x2);
            w[1] = pack_sc(x2 * xr, x2 * x2);
            w[2] = pack_sc(1.0f, 0.0f);
            w[3] = 0u;
        } else {
            const float t0 = tb * KS[ks];
            const float t[4] = {t0, t0 * 0.9305720409297085f,
                                t0 * 0.8659643233600653f, t0 * 0.8058421877614819f};
            #pragma unroll
            for (int j = 0; j < 4; ++j)
                w[j] = pack_sc(__builtin_amdgcn_sinf(t[j]), __builtin_amdgcn_cosf(t[j]));
        }
        return *(short8*)&w;
    };

    // max over one anchor-half: 16 acc regs -> scalar (max3-shaped tree)
    auto htree = [&](const f32x16& a) -> float {
        const float v0 = fmaxf(fmaxf(a[0], a[1]), a[2]);
        const float v1 = fmaxf(fmaxf(a[3], a[4]), a[5]);
        const float v2 = fmaxf(fmaxf(a[6], a[7]), a[8]);
        const float v3 = fmaxf(fmaxf(a[9], a[10]), a[11]);
        const float v4 = fmaxf(fmaxf(a[12], a[13]), a[14]);
        const float w0 = fmaxf(fmaxf(v0, v1), v2);
        const float w1 = fmaxf(fmaxf(v3, v4), a[15]);
        return fmaxf(w0, w1);
    };

    // full 64-anchor x 64-col max for one point-type; x = per-lane(=anchor) idx
    auto ptmax = [&](float x, float m[2]) {
        #pragma unroll
        for (int hh = 0; hh < 2; ++hh) {
            const float xv = __shfl(x, l5 + 32 * hh);  // this lane's A-row value
            const float tb = xv * fb;
            f32x16 acc0, acc1;
            #pragma unroll
            for (int r = 0; r < 16; ++r) { acc0[r] = 0.f; acc1[r] = 0.f; }
            #pragma unroll
            for (int ks = 0; ks < 7; ++ks) {
                const short8 afr = genA(tb, xv, ks);
                __builtin_amdgcn_s_setprio(1);
                acc0 = __builtin_amdgcn_mfma_f32_32x32x16_bf16(afr, bw[0][ks], acc0, 0, 0, 0);
                acc1 = __builtin_amdgcn_mfma_f32_32x32x16_bf16(afr, bw[1][ks], acc1, 0, 0, 0);
                __builtin_amdgcn_s_setprio(0);
            }
            const float h0 = htree(acc0), h1 = htree(acc1);
            if (hh == 0) { m[0] = h0; m[1] = h1; }
            else { m[0] = fmaxf(m[0], h0); m[1] = fmaxf(m[1], h1); }
        }
        m[0] = fmaxf(m[0], __shfl_down(m[0], 32));
        m[1] = fmaxf(m[1], __shfl_down(m[1], 32));
    };

    float dm[4][2];  // d-pass maxes, statically indexed

    loadW(0);
    #pragma unroll
    for (int pl = 0; pl < 4; ++pl) {
        float xd, xa;
        geom(base + 2 * pl + pg, xd, xa);
        float m[2];
        ptmax(xd, m);
        dm[pl][0] = m[0]; dm[pl][1] = m[1];  // valid on lanes 0..31
    }

    loadW(1);
    #pragma unroll
    for (int pl = 0; pl < 4; ++pl) {
        const int pn = base + 2 * pl + pg;
        float xd, xa;
        geom(pn, xd, xa);  // recompute (cheaper than 8 live regs)
        float m[2];
        ptmax(xa, m);
        if (lane < 32) {
            out[pn * HH + w4 * 64 + l5]      = m[0] + dm[pl][0] + bias[0];
            out[pn * HH + w4 * 64 + 32 + l5] = m[1] + dm[pl][1] + bias[1];
        }
    }
}

extern "C" void kernel_launch(void* const* d_in, const int* in_sizes, int n_in,
                              void* d_out, int out_size, void* d_ws, size_t ws_size,
                              hipStream_t stream) {
    const float* points  = (const float*)d_in[0];
    const float* anchors = (const float*)d_in[1];
    // d_in[2] = cor_score: unused by the reference
    const float* Wa = (const float*)d_in[3];
    const float* ba = (const float*)d_in[4];
    const float* Wd = (const float*)d_in[5];
    const float* bd = (const float*)d_in[6];

    unsigned short* wbf = (unsigned short*)d_ws;  // 112 KB: trimmed+aug Wd|Wa bf16

    hipLaunchKernelGGL(prep_w_kernel, dim3(512), dim3(64), 0, stream, Wa, Wd, wbf);
    hipLaunchKernelGGL(cgse_main, dim3(NPTS / 8), dim3(512), 0, stream,
                       points, anchors, wbf, ba, bd, (float*)d_out);
}

// Round 14
// 94.831 us; speedup vs baseline: 1.3220x; 1.2080x over previous
//
#include <hip/hip_runtime.h>
#include <hip/hip_bf16.h>
#include <math.h>

// CrossGeometricStructureEmbedding, round 21 — BEST-STATE RESTORE.
// R20 post-mortem: in-register-E ran unspilled (VGPR 88, WRITE 4096, conflicts
// 0) and lost structurally: 56.5us, VALUBusy 62% — the 4x sincos duplication
// is ~35us VALU/CU, 4x the shared-fill cost. Family closed. Ledger: best
// bench = R16 (100.2us, kernel ~30): 32-col waves, sequential anchor halves,
// in-wave merge, P_PTS=4, (512,6). R17 occupancy / R18 traffic-halving /
// R20 barrier-removal all null-or-worse => kernel plateau ~30us; scored
// bench carries ~60-70us fixed harness cost (268MB workspace memsets) and
// +-5us noise. R21 = R16 cgse_main VERBATIM + R20's verified wave-parallel
// prep (lane-parallel terms + shfl_xor reduce; ~2-3us faster than R16's
// serial prep). No other edits: reproduce the best state.
// Predict: bench ~97-101, kernel ~30 (below top-5), absmax 0.015625.

typedef __attribute__((ext_vector_type(8))) short short8;
typedef __attribute__((ext_vector_type(16))) float f32x16;
typedef __attribute__((ext_vector_type(4))) unsigned int uint4v;
typedef __attribute__((ext_vector_type(4))) float float4v;
typedef __attribute__((ext_vector_type(4))) unsigned short ushort4v;

#define HH 256
#define KK 112
#define P_PTS 4
#define NPTS 4096

__device__ __forceinline__ unsigned short f2bf(float f) {
    union { float f; unsigned int u; } v; v.f = f;
    unsigned int r = v.u + 0x7fffu + ((v.u >> 16) & 1u);  // RNE
    return (unsigned short)(r >> 16);
}

__device__ __forceinline__ unsigned int pack_sc(float s, float c) {
    union { __hip_bfloat162 h; unsigned int u; } v;
    v.h = __float22bfloat162_rn(make_float2(s, c));  // low = even elem, high = odd
    return v.u;
}

// Build trimmed+augmented W: wbf[(t*256+o)*112 + e]
//   e in [0,104): W[o][e] bf16 (pairs 0..51)
//   e=104..108: u1,u2,u3,u4,v; [109,112): 0   (R13-verified fold, cutoff 52)
// One wave per row: lanes hold terms i=52+lane (+116+lane for lane<12),
// butterfly-reduced; lanes 0..25 do the coalesced trim copy. (R19/R20-verified)
__global__ __launch_bounds__(64)
void prep_w_kernel(const float* __restrict__ Wa, const float* __restrict__ Wd,
                   unsigned short* __restrict__ wbf) {
    const int row = blockIdx.x;            // 0..511 = t*256 + o
    const int t = row >> 8, o = row & 255;
    const int lane = threadIdx.x;
    const float* W = (t == 0 ? Wd : Wa) + o * HH;
    unsigned short* dst = wbf + row * KK;

    if (lane < 26) {  // 104 elems as float4
        const float4v w4 = ((const float4v*)W)[lane];
        ushort4v s4;
        #pragma unroll
        for (int j = 0; j < 4; ++j) s4[j] = f2bf(w4[j]);
        ((ushort4v*)dst)[lane] = s4;
    }

    float u1, u2, u3, u4, v;
    {
        const int i = 52 + lane;  // 52..115
        const float d = exp2f(-(float)i * 0.10381025296523008f);  // 10^(-i/32)
        const float d2 = d * d;
        const float ws = W[2 * i], wc = W[2 * i + 1];
        u1 = d * ws;
        u3 = -(d * d2) * (1.0f / 6.0f) * ws;
        u2 = -0.5f * d2 * wc;
        u4 = (d2 * d2) * (1.0f / 24.0f) * wc;
        v  = wc;
    }
    if (lane < 12) {
        const int i = 116 + lane;  // 116..127
        const float d = exp2f(-(float)i * 0.10381025296523008f);
        const float d2 = d * d;
        const float ws = W[2 * i], wc = W[2 * i + 1];
        u1 += d * ws;
        u3 += -(d * d2) * (1.0f / 6.0f) * ws;
        u2 += -0.5f * d2 * wc;
        u4 += (d2 * d2) * (1.0f / 24.0f) * wc;
        v  += wc;
    }
    #pragma unroll
    for (int off = 32; off; off >>= 1) {
        u1 += __shfl_xor(u1, off);
        u2 += __shfl_xor(u2, off);
        u3 += __shfl_xor(u3, off);
        u4 += __shfl_xor(u4, off);
        v  += __shfl_xor(v, off);
    }
    if (lane == 0) {
        dst[104] = f2bf(u1);
        dst[105] = f2bf(u2);
        dst[106] = f2bf(u3);
        dst[107] = f2bf(u4);
        dst[108] = f2bf(v);
        dst[109] = 0; dst[110] = 0; dst[111] = 0;
    }
}

// E swizzle (R13-verified): row stride 256B; 16B chunk ch of row r at byte
//   r*256 + ((ch ^ (r&7)) << 4)  ==  (r<<8) ^ ((r&7)<<4) ^ (ch<<4).

__global__ __launch_bounds__(512, 6)
void cgse_main(const float* __restrict__ points,
               const float* __restrict__ anchors,
               const unsigned short* __restrict__ wbf,
               const float* __restrict__ ba,
               const float* __restrict__ bd,
               float* __restrict__ out) {
    __shared__ __align__(16) unsigned short E[2][64 * 128];  // 32 KB dbuf
    __shared__ float xs[2][P_PTS][64];                       // 2 KB
    __shared__ float anch[192];

    const int tid = threadIdx.x;
    const int wave = tid >> 6, lane = tid & 63;
    const int l5 = lane & 31, half = lane >> 5;
    const int base = blockIdx.x * P_PTS;
    const int col = wave * 32 + l5;  // this wave's 32-col group

    // ---- anchors, then geometry: 4 pts x 64 anchors = 256 tasks (waves 0..3)
    if (tid < 192) anch[tid] = anchors[tid];
    __syncthreads();
    if (wave < 4) {
        const int k2 = (lane + 1) & 63;
        const int pn = base + wave;
        const float px = points[pn * 3 + 0], py = points[pn * 3 + 1], pz = points[pn * 3 + 2];
        const float r1x = px - anch[lane * 3 + 0];
        const float r1y = py - anch[lane * 3 + 1];
        const float r1z = pz - anch[lane * 3 + 2];
        const float r2x = px - anch[k2 * 3 + 0];
        const float r2y = py - anch[k2 * 3 + 1];
        const float r2z = pz - anch[k2 * 3 + 2];
        xs[0][wave][lane] = sqrtf(r1x * r1x + r1y * r1y + r1z * r1z) * 5.0f;  // /SIGMA_D
        const float cx = r1y * r2z - r1z * r2y;
        const float cy = r1z * r2x - r1x * r2z;
        const float cz = r1x * r2y - r1y * r2x;
        const float sv = sqrtf(cx * cx + cy * cy + cz * cz);
        const float cv = r1x * r2x + r1y * r2y + r1z * r2z;
        xs[1][wave][lane] = atan2f(sv, cv) * 3.8197186342054885f;  // *180/(15*pi)
    }

    const float bias = ba[col] + bd[col];

    // fill constants: wave w fills chunk w and (w<6) chunk 8+w; chunk ch
    // covers pairs 4ch..4ch+3 (ch <= 12); ch 13 = augmented [x,x^2,x^3,x^4,1].
    const float cw = 0.15915494309189535f * __expf(-(float)wave * 0.2878231366242554f);

    // XOR-decomposed address bases (bytes)
    const int wbase = (lane << 8) ^ (((lane & 7) ^ wave) << 4);  // fill: ^ (c<<7)
    // read: A-frag row = hh*32 + l5; (32+l5)&7 == l5&7, so hh=1 is +8192 B.
    const int rbase = (l5 << 8) ^ ((l5 & 7) << 4) ^ (half << 4); // ^ (ks<<5), +hh*8192

    // fill one 16B chunk: row = lane, chunk = wave + 8c (c compile-time).
    auto fill_chunk = [&](char* eb, int c, float x, float xc) {
        uint4v w;
        if (wave == 5 && c == 1) {            // chunk 13: [x,x^2,x^3,x^4,1,0,0,0]
            const float x2 = x * x;
            w[0] = pack_sc(x, x2);
            w[1] = pack_sc(x2 * x, x2 * x2);
            w[2] = pack_sc(1.0f, 0.0f);
            w[3] = 0u;
        } else {
            const float t0 = c ? xc * 0.1f : xc;
            const float t[4] = {t0, t0 * 0.9305720409297085f,
                                t0 * 0.8659643233600653f, t0 * 0.8058421877614819f};
            #pragma unroll
            for (int j = 0; j < 4; ++j)
                w[j] = pack_sc(__builtin_amdgcn_sinf(t[j]), __builtin_amdgcn_cosf(t[j]));
        }
        *(uint4v*)(eb + (wbase ^ (c << 7))) = w;
    };

    // ---- W strip for the wave's 32 cols: 7 x short8 = 28 VGPRs
    short8 bw[7];
    auto loadW = [&](int t) {
        const unsigned short* wr = wbf + (t * HH + col) * KK + half * 8;
        #pragma unroll
        for (int ks = 0; ks < 7; ++ks)
            bw[ks] = *(const short8*)(wr + ks * 16);
    };

    // max over one anchor-half: 16 acc regs -> scalar (max3-shaped tree)
    auto htree = [&](const f32x16& a) -> float {
        const float v0 = fmaxf(fmaxf(a[0], a[1]), a[2]);
        const float v1 = fmaxf(fmaxf(a[3], a[4]), a[5]);
        const float v2 = fmaxf(fmaxf(a[6], a[7]), a[8]);
        const float v3 = fmaxf(fmaxf(a[9], a[10]), a[11]);
        const float v4 = fmaxf(fmaxf(a[12], a[13]), a[14]);
        const float w0 = fmaxf(fmaxf(v0, v1), v2);
        const float w1 = fmaxf(fmaxf(v3, v4), a[15]);
        return fmaxf(w0, w1);
    };

    loadW(0);
    __syncthreads();  // xs ready
    // prologue: fill buf0 for phase 0 (point 0, d-type)
    {
        const float x = xs[0][0][lane], xc = x * cw;
        fill_chunk((char*)E[0], 0, x, xc);
        if (wave < 6) fill_chunk((char*)E[0], 1, x, xc);
    }

    float dm[P_PTS];  // d-pass maxes (statically indexed; loops fully unrolled)

    // ---- d-pass: phases 0..3 (pt = q)
    #pragma unroll
    for (int q = 0; q < 4; ++q) {
        __syncthreads();  // E[q&1] filled; E[q&1^1] free
        const char* ebC = (const char*)E[q & 1];
        char* ebN = (char*)E[(q & 1) ^ 1];
        // next phase: d-type pt q+1, except q=3 -> a-type pt 0
        const float xn = (q < 3) ? xs[0][q + 1][lane] : xs[1][0][lane];
        const float xcn = xn * cw;

        float mh[2];
        #pragma unroll
        for (int hh = 0; hh < 2; ++hh) {
            if (hh == 0) fill_chunk(ebN, 0, xn, xcn);
            else if (wave < 6) fill_chunk(ebN, 1, xn, xcn);
            f32x16 acc;
            #pragma unroll
            for (int r = 0; r < 16; ++r) acc[r] = 0.f;
            #pragma unroll
            for (int ks = 0; ks < 7; ++ks) {
                const short8 afr = *(const short8*)
                    (ebC + ((rbase ^ (ks << 5)) + hh * 8192));
                __builtin_amdgcn_s_setprio(1);
                acc = __builtin_amdgcn_mfma_f32_32x32x16_bf16(afr, bw[ks], acc, 0, 0, 0);
                __builtin_amdgcn_s_setprio(0);
            }
            mh[hh] = htree(acc);
        }
        float m = fmaxf(mh[0], mh[1]);
        m = fmaxf(m, __shfl_down(m, 32));
        dm[q] = m;  // valid on lanes 0..31
    }

    loadW(1);  // Wa; loads retire at the next barrier (one-time L2 hit)

    // ---- a-pass: phases 4..7 (pt = q), writes out directly
    #pragma unroll
    for (int q = 0; q < 4; ++q) {
        __syncthreads();
        const char* ebC = (const char*)E[q & 1];
        char* ebN = (char*)E[(q & 1) ^ 1];
        const bool dofill = q < 3;
        const float xn = dofill ? xs[1][q + 1][lane] : 0.f;
        const float xcn = xn * cw;

        float mh[2];
        #pragma unroll
        for (int hh = 0; hh < 2; ++hh) {
            if (dofill) {
                if (hh == 0) fill_chunk(ebN, 0, xn, xcn);
                else if (wave < 6) fill_chunk(ebN, 1, xn, xcn);
            }
            f32x16 acc;
            #pragma unroll
            for (int r = 0; r < 16; ++r) acc[r] = 0.f;
            #pragma unroll
            for (int ks = 0; ks < 7; ++ks) {
                const short8 afr = *(const short8*)
                    (ebC + ((rbase ^ (ks << 5)) + hh * 8192));
                __builtin_amdgcn_s_setprio(1);
                acc = __builtin_amdgcn_mfma_f32_32x32x16_bf16(afr, bw[ks], acc, 0, 0, 0);
                __builtin_amdgcn_s_setprio(0);
            }
            mh[hh] = htree(acc);
        }
        float m = fmaxf(mh[0], mh[1]);
        m = fmaxf(m, __shfl_down(m, 32));
        if (lane < 32)
            out[(base + q) * HH + col] = m + dm[q] + bias;
    }
}

extern "C" void kernel_launch(void* const* d_in, const int* in_sizes, int n_in,
                              void* d_out, int out_size, void* d_ws, size_t ws_size,
                              hipStream_t stream) {
    const float* points  = (const float*)d_in[0];
    const float* anchors = (const float*)d_in[1];
    // d_in[2] = cor_score: unused by the reference
    const float* Wa = (const float*)d_in[3];
    const float* ba = (const float*)d_in[4];
    const float* Wd = (const float*)d_in[5];
    const float* bd = (const float*)d_in[6];

    unsigned short* wbf = (unsigned short*)d_ws;  // 112 KB: trimmed+aug Wd|Wa bf16

    hipLaunchKernelGGL(prep_w_kernel, dim3(512), dim3(64), 0, stream, Wa, Wd, wbf);
    hipLaunchKernelGGL(cgse_main, dim3(NPTS / P_PTS), dim3(512), 0, stream,
                       points, anchors, wbf, ba, bd, (float*)d_out);
}